// Round 6
// baseline (33.236 us; speedup 1.0000x reference)
//
#include <hip/hip_runtime.h>

// out[n,k] = sum_{i,j} x[n,i] * W[k,i,j] * x[n,j]   (N=262144 rows, D=32)
// GEMM form: z[n, p=i*32+j] = x[n,i]*x[n,j];  out = z (N x 1024) @ Wf (1024 x 32),
// Wf[p][k] = W[k*1024 + p].  v_mfma_f32_32x32x16_f16, fp32 accumulate.
//
// R6 vs R5 (31.5us): LDS/barrier structure + suspected K-loop spill removed.
//  - prep kernel writes the f16 B-fragment table (64 KiB, fragment order) to
//    d_ws; main kernel loads bfrags from L2 (coalesced 1KiB/instr, table is
//    L2-resident on every XCD). No LDS, no __syncthreads in the main kernel.
//  - K-loop grouped 4 steps/group: each group uses exactly one xpk pair-reg
//    (ii>>1 == t), bounding bfrag live ranges (no 64-wide hoist -> no spill).
//  - 256-thr blocks x 1024, launch_bounds(256,2): reg cap 256, spill
//    impossible; 3-4 independent blocks/CU, latency hidden by TLP not phases.

typedef _Float16 f16x2 __attribute__((ext_vector_type(2)));
typedef _Float16 f16x8 __attribute__((ext_vector_type(8)));
typedef float    f32x16 __attribute__((ext_vector_type(16)));

static __device__ __forceinline__ unsigned int pk2_f16(float lo, float hi) {
    return __builtin_bit_cast(unsigned int, __builtin_amdgcn_cvt_pkrtz(lo, hi));
}

// ---- prep: build f16 fragment table in ws ----
// bt[(s*64 + l)] (16B) = f16 of Wf[16s + (l>>5)*8 + b][l&31], b=0..7
//                      = f16 of W[(l&31)*1024 + s*16 + (l>>5)*8 + b]
__global__ __launch_bounds__(512)
void prep_btab(const float* __restrict__ W, uint4* __restrict__ bt) {
    int idx = blockIdx.x * 512 + threadIdx.x;     // 0..4095
    int s = idx >> 6;
    int l = idx & 63;
    const float* src = W + (l & 31) * 1024 + s * 16 + ((l >> 5) << 3);
    float4 w0 = *(const float4*)(src);
    float4 w1 = *(const float4*)(src + 4);
    uint4 pk;
    pk.x = pk2_f16(w0.x, w0.y);
    pk.y = pk2_f16(w0.z, w0.w);
    pk.z = pk2_f16(w1.x, w1.y);
    pk.w = pk2_f16(w1.z, w1.w);
    bt[idx] = pk;
}

__global__ __launch_bounds__(256, 2)
void quadform_kernel(const float* __restrict__ x,
                     const uint4* __restrict__ bt,
                     float* __restrict__ out) {
    const int tid  = threadIdx.x;
    const int lane = tid & 63;
    const int wave = tid >> 6;
    const int hi   = lane >> 5;
    const int rl   = lane & 31;
    const long rowbase = (long)blockIdx.x * 256 + wave * 64;

    // ---- load this lane's 2 rows, pack to f16 pairs ----
    unsigned int xpk[2][16];   // (x[2c], x[2c+1]) packed f16
    #pragma unroll
    for (int r = 0; r < 2; ++r) {
        const float4* xr = (const float4*)(x + (rowbase + r * 32 + rl) * 32);
        #pragma unroll
        for (int c = 0; c < 8; ++c) {
            float4 v = xr[c];
            xpk[r][2 * c + 0] = pk2_f16(v.x, v.y);
            xpk[r][2 * c + 1] = pk2_f16(v.z, v.w);
        }
    }

    // xsel[r][q*4+t]: pair-reg feeding A-slots (b=2t,2t+1) for step parity q:
    //   j = q*16 + hi*8 + 2t  ->  pair index c = q*8 + hi*4 + t
    unsigned int xsel[2][8];
    #pragma unroll
    for (int r = 0; r < 2; ++r)
        #pragma unroll
        for (int q = 0; q < 2; ++q)
            #pragma unroll
            for (int t = 0; t < 4; ++t)
                xsel[r][q * 4 + t] = hi ? xpk[r][q * 8 + 4 + t] : xpk[r][q * 8 + t];

    f32x16 acc[2];
    #pragma unroll
    for (int r = 0; r < 2; ++r)
        #pragma unroll
        for (int e = 0; e < 16; ++e) acc[r][e] = 0.0f;

    // ---- K loop: 16 groups of 4 steps (s = 4g+u); each group uses only
    //      xpk[r][g] (ii>>1 == g within the group) ----
    #pragma unroll
    for (int g = 0; g < 16; ++g) {
        uint4 bf[4];
        #pragma unroll
        for (int u = 0; u < 4; ++u)
            bf[u] = bt[(4 * g + u) * 64 + lane];   // L2-resident, coalesced
        #pragma unroll
        for (int u = 0; u < 4; ++u) {
            const int q = u & 1;                               // s&1
            const unsigned int sel = (u >= 2) ? 0x03020302u    // ii odd
                                              : 0x01000100u;   // ii even
            #pragma unroll
            for (int r = 0; r < 2; ++r) {
                unsigned int w = xpk[r][g];
                f16x2 xi2 = __builtin_bit_cast(f16x2, __builtin_amdgcn_perm(w, w, sel));
                union { f16x8 v; unsigned int uu[4]; } a;
                #pragma unroll
                for (int t = 0; t < 4; ++t) {
                    f16x2 p = xi2 * __builtin_bit_cast(f16x2, xsel[r][q * 4 + t]);
                    a.uu[t] = __builtin_bit_cast(unsigned int, p);
                }
                acc[r] = __builtin_amdgcn_mfma_f32_32x32x16_f16(
                             a.v, __builtin_bit_cast(f16x8, bf[u]), acc[r], 0, 0, 0);
            }
        }
    }

    // ---- store: col = lane&31 (k), row = (e&3) + 8*(e>>2) + 4*hi ----
    #pragma unroll
    for (int r = 0; r < 2; ++r) {
        long n0 = rowbase + r * 32;
        #pragma unroll
        for (int e = 0; e < 16; ++e) {
            int row = (e & 3) + 8 * (e >> 2) + 4 * hi;
            out[(n0 + row) * 32 + rl] = acc[r][e];
        }
    }
}

extern "C" void kernel_launch(void* const* d_in, const int* in_sizes, int n_in,
                              void* d_out, int out_size, void* d_ws, size_t ws_size,
                              hipStream_t stream) {
    const float* x = (const float*)d_in[0];
    const float* W = (const float*)d_in[1];
    float* out = (float*)d_out;
    uint4* bt = (uint4*)d_ws;                  // 64 KiB fragment table

    prep_btab<<<8, 512, 0, stream>>>(W, bt);
    int nrows = in_sizes[0] / 32;              // 262144
    int grid  = nrows / 256;                   // 1024 blocks of 256 thr
    quadform_kernel<<<grid, 256, 0, stream>>>(x, bt, out);
}